// Round 1
// baseline (232.485 us; speedup 1.0000x reference)
//
#include <hip/hip_runtime.h>
#include <hip/hip_bf16.h>
#include <stdint.h>
#include <stddef.h>

#define NVOX 262144
#define CCH 128
#define BN_EPS 1e-3f

typedef __attribute__((ext_vector_type(8))) short bfrag;   // 8 bf16 = 4 VGPRs
typedef __attribute__((ext_vector_type(4))) float f4;      // 4 f32

__device__ __forceinline__ unsigned short f2bf(float f) {
  union { float f; unsigned u; } v; v.f = f;
  unsigned r = v.u + 0x7fffu + ((v.u >> 16) & 1u);   // RNE (inputs are finite)
  return (unsigned short)(r >> 16);
}

__device__ __forceinline__ bfrag pack8(f4 x, f4 y) {
  bfrag r;
  r[0] = (short)f2bf(x[0]); r[1] = (short)f2bf(x[1]);
  r[2] = (short)f2bf(x[2]); r[3] = (short)f2bf(x[3]);
  r[4] = (short)f2bf(y[0]); r[5] = (short)f2bf(y[1]);
  r[6] = (short)f2bf(y[2]); r[7] = (short)f2bf(y[3]);
  return r;
}

__device__ __forceinline__ float sigmoidf_(float x) {
  return 1.f / (1.f + __expf(-x));
}

// ---------------------------------------------------------------------------
// Pre-swizzle W1/W2/W3 into MFMA B-fragment order, bf16:
// wf[frag][lane][8], frag = ((conv*3+tap)*4 + kc)*8 + tile
// lane holds B[k = kc*32 + (lane>>4)*8 + e][col = tile*16 + (lane&15)]
// ---------------------------------------------------------------------------
__global__ void prep_wfrag(const float* __restrict__ W1, const float* __restrict__ W2,
                           const float* __restrict__ W3, unsigned short* __restrict__ wf) {
  const int frag = blockIdx.x;           // 0..287
  const int tile = frag & 7;
  const int kc   = (frag >> 3) & 3;
  const int tap  = (frag >> 5) % 3;
  const int conv = frag / 96;
  const float* W = (conv == 0) ? W1 : ((conv == 1) ? W2 : W3);
  const int l   = threadIdx.x;           // 0..63
  const int col = tile * 16 + (l & 15);
  const int k0  = kc * 32 + (l >> 4) * 8;
  bfrag o;
#pragma unroll
  for (int e = 0; e < 8; ++e)
    o[e] = (short)f2bf(W[(size_t)(tap * CCH + k0 + e) * CCH + col]);
  *reinterpret_cast<bfrag*>(wf + (size_t)frag * 512 + l * 8) = o;
}

// ---------------------------------------------------------------------------
// Fused main kernel: BM=64 rows/block, 256 threads (4 waves x 16 rows x 128 cols)
// ---------------------------------------------------------------------------
__global__ __launch_bounds__(256, 2)
void recon_main(const float* __restrict__ feats,
                const int* __restrict__ nbrz, const int* __restrict__ nbry,
                const int* __restrict__ nbrx,
                const unsigned short* __restrict__ wfrag,
                const float* __restrict__ g0, const float* __restrict__ b0,
                const float* __restrict__ m0, const float* __restrict__ v0,
                const float* __restrict__ g2, const float* __restrict__ b2,
                const float* __restrict__ m2, const float* __restrict__ v2,
                const float* __restrict__ g3, const float* __restrict__ b3,
                const float* __restrict__ m3, const float* __restrict__ v3,
                float* __restrict__ out) {
  __shared__ unsigned short Alds[64][136];   // +8 bf16 pad -> 2-way (free) on reads
  __shared__ unsigned short Blds[16384];     // 32 KB fragment-ordered B tile

  const int tid  = threadIdx.x;
  const int lane = tid & 63;
  const int wave = tid >> 6;
  const int row0 = blockIdx.x * 64;

  f4 acc[3][8];
#pragma unroll
  for (int c = 0; c < 3; ++c)
#pragma unroll
    for (int t = 0; t < 8; ++t) acc[c][t] = f4{0.f, 0.f, 0.f, 0.f};

  const int gr   = tid >> 2;          // gather row 0..63 (4 threads/row)
  const int gch  = (tid & 3) * 32;    // 32-channel chunk
  const int arow = wave * 16 + (lane & 15);
  const int asub = (lane >> 4) * 8;

#pragma unroll
  for (int conv = 0; conv < 3; ++conv) {
    const int* nbr = (conv == 0) ? nbrz : ((conv == 1) ? nbry : nbrx);
    for (int tap = 0; tap < 3; ++tap) {
      // ---- stage B: 32 KB, direct global->LDS (linear, coalesced) ----
      {
        const unsigned short* src = wfrag + ((size_t)(conv * 3 + tap) << 14);
#pragma unroll
        for (int i = 0; i < 8; ++i) {
          const int off = (wave << 13) + (i << 10);   // byte offset, wave-uniform
          __builtin_amdgcn_global_load_lds(
              (__attribute__((address_space(1))) void*)(src + (off >> 1) + lane * 8),
              (__attribute__((address_space(3))) void*)((char*)Blds + off),
              16, 0, 0);
        }
      }
      // ---- stage A: gather 64 neighbor rows, fp32 -> bf16 ----
      {
        const int idx    = nbr[(row0 + gr) * 3 + tap];
        const bool valid = ((unsigned)idx < (unsigned)NVOX);   // sentinel == NVOX
        const float* src = feats + ((size_t)(valid ? idx : 0) << 7) + gch;
        const float zm   = valid ? 1.f : 0.f;
#pragma unroll
        for (int j = 0; j < 4; ++j) {
          f4 x = *reinterpret_cast<const f4*>(src + j * 8);
          f4 y = *reinterpret_cast<const f4*>(src + j * 8 + 4);
          x *= zm; y *= zm;
          *reinterpret_cast<bfrag*>(&Alds[gr][gch + j * 8]) = pack8(x, y);
        }
      }
      __syncthreads();
      // ---- MFMA: K=128 in 4 chunks of 32, 8 col-tiles ----
#pragma unroll
      for (int kc = 0; kc < 4; ++kc) {
        const bfrag a = *reinterpret_cast<const bfrag*>(&Alds[arow][kc * 32 + asub]);
#pragma unroll
        for (int t = 0; t < 8; ++t) {
          const bfrag b = *reinterpret_cast<const bfrag*>(
              &Blds[(((kc << 3) + t) << 9) + lane * 8]);
          acc[conv][t] = __builtin_amdgcn_mfma_f32_16x16x32_bf16(a, b, acc[conv][t], 0, 0, 0);
        }
      }
      __syncthreads();
    }
  }

  // ---- epilogue: BN + sigmoid chains, sum, multiply by features ----
  const int colb = lane & 15;
  const int rb   = row0 + wave * 16 + ((lane >> 4) << 2);
#pragma unroll
  for (int t = 0; t < 8; ++t) {
    const int col = t * 16 + colb;
    const float sc0 = g0[col] * rsqrtf(v0[col] + BN_EPS);
    const float sh0 = b0[col] - m0[col] * sc0;
    const float sc2 = g2[col] * rsqrtf(v2[col] + BN_EPS);
    const float sh2 = b2[col] - m2[col] * sc2;
    const float sc3 = g3[col] * rsqrtf(v3[col] + BN_EPS);
    const float sh3 = b3[col] - m3[col] * sc3;
#pragma unroll
    for (int j = 0; j < 4; ++j) {
      const int row = rb + j;
      float u = sigmoidf_(sc0 * acc[0][t][j] + sh0);
      u       = sigmoidf_(sc2 * u + sh2);
      const float s3v  = sigmoidf_(sc3 * acc[2][t][j] + sh3);
      const float ssum = u + acc[1][t][j] + s3v;
      const size_t o   = ((size_t)row << 7) + col;
      out[o] = ssum * feats[o];
    }
  }
}

// ---------------------------------------------------------------------------
// Fallback (only if d_ws is too small): exact fp32, slow but correct.
// ---------------------------------------------------------------------------
__global__ void recon_naive(const float* __restrict__ feats,
    const float* __restrict__ W1, const float* __restrict__ W2, const float* __restrict__ W3,
    const int* __restrict__ nbrz, const int* __restrict__ nbry, const int* __restrict__ nbrx,
    const float* g0, const float* b0, const float* m0, const float* v0,
    const float* g2, const float* b2, const float* m2, const float* v2,
    const float* g3, const float* b3, const float* m3, const float* v3,
    float* __restrict__ out) {
  __shared__ float rows[3][CCH];
  const int n = blockIdx.x;
  const int d = threadIdx.x;
  float res[3];
#pragma unroll
  for (int conv = 0; conv < 3; ++conv) {
    const int* nbr  = (conv == 0) ? nbrz : ((conv == 1) ? nbry : nbrx);
    const float* W  = (conv == 0) ? W1 : ((conv == 1) ? W2 : W3);
#pragma unroll
    for (int tap = 0; tap < 3; ++tap) {
      const int idx = nbr[n * 3 + tap];
      rows[tap][d] = ((unsigned)idx < (unsigned)NVOX) ? feats[((size_t)idx << 7) + d] : 0.f;
    }
    __syncthreads();
    const float* rflat = &rows[0][0];
    float s = 0.f;
    for (int k = 0; k < 3 * CCH; ++k) s += rflat[k] * W[(size_t)k * CCH + d];
    res[conv] = s;
    __syncthreads();
  }
  const float sc0 = g0[d] * rsqrtf(v0[d] + BN_EPS), sh0 = b0[d] - m0[d] * sc0;
  const float sc2 = g2[d] * rsqrtf(v2[d] + BN_EPS), sh2 = b2[d] - m2[d] * sc2;
  const float sc3 = g3[d] * rsqrtf(v3[d] + BN_EPS), sh3 = b3[d] - m3[d] * sc3;
  float u = sigmoidf_(sc0 * res[0] + sh0);
  u = sigmoidf_(sc2 * u + sh2);
  const float s3v = sigmoidf_(sc3 * res[2] + sh3);
  out[((size_t)n << 7) + d] = (u + res[1] + s3v) * feats[((size_t)n << 7) + d];
}

extern "C" void kernel_launch(void* const* d_in, const int* in_sizes, int n_in,
                              void* d_out, int out_size, void* d_ws, size_t ws_size,
                              hipStream_t stream) {
  const float* feats = (const float*)d_in[0];
  const float* W1 = (const float*)d_in[1];
  const float* W2 = (const float*)d_in[2];
  const float* W3 = (const float*)d_in[3];
  const float* g0 = (const float*)d_in[4];
  const float* b0 = (const float*)d_in[5];
  const float* m0 = (const float*)d_in[6];
  const float* v0 = (const float*)d_in[7];
  const float* g2 = (const float*)d_in[8];
  const float* b2 = (const float*)d_in[9];
  const float* m2 = (const float*)d_in[10];
  const float* v2 = (const float*)d_in[11];
  const float* g3 = (const float*)d_in[12];
  const float* b3 = (const float*)d_in[13];
  const float* m3 = (const float*)d_in[14];
  const float* v3 = (const float*)d_in[15];
  const int* nz = (const int*)d_in[16];
  const int* ny = (const int*)d_in[17];
  const int* nx = (const int*)d_in[18];
  float* out = (float*)d_out;

  const size_t wf_bytes = 288u * 1024u;   // 288 fragments * 1 KB
  if (ws_size >= wf_bytes) {
    unsigned short* wf = (unsigned short*)d_ws;
    hipLaunchKernelGGL(prep_wfrag, dim3(288), dim3(64), 0, stream, W1, W2, W3, wf);
    hipLaunchKernelGGL(recon_main, dim3(NVOX / 64), dim3(256), 0, stream,
                       feats, nz, ny, nx, wf,
                       g0, b0, m0, v0, g2, b2, m2, v2, g3, b3, m3, v3, out);
  } else {
    hipLaunchKernelGGL(recon_naive, dim3(NVOX), dim3(CCH), 0, stream,
                       feats, W1, W2, W3, nz, ny, nx,
                       g0, b0, m0, v0, g2, b2, m2, v2, g3, b3, m3, v3, out);
  }
}

// Round 2
// 213.661 us; speedup vs baseline: 1.0881x; 1.0881x over previous
//
#include <hip/hip_runtime.h>
#include <hip/hip_bf16.h>
#include <stdint.h>
#include <stddef.h>

#define NVOX 262144
#define CCH 128
#define BN_EPS 1e-3f

typedef __attribute__((ext_vector_type(8))) short bfrag;   // 8 bf16 = 4 VGPRs
typedef __attribute__((ext_vector_type(4))) float f4;      // 4 f32

__device__ __forceinline__ unsigned short f2bf(float f) {
  union { float f; unsigned u; } v; v.f = f;
  unsigned r = v.u + 0x7fffu + ((v.u >> 16) & 1u);   // RNE (inputs finite)
  return (unsigned short)(r >> 16);
}

__device__ __forceinline__ bfrag pack8(f4 x, f4 y) {
  bfrag r;
  r[0] = (short)f2bf(x[0]); r[1] = (short)f2bf(x[1]);
  r[2] = (short)f2bf(x[2]); r[3] = (short)f2bf(x[3]);
  r[4] = (short)f2bf(y[0]); r[5] = (short)f2bf(y[1]);
  r[6] = (short)f2bf(y[2]); r[7] = (short)f2bf(y[3]);
  return r;
}

__device__ __forceinline__ float sigmoidf_(float x) {
  return 1.f / (1.f + __expf(-x));
}

// ---------------------------------------------------------------------------
// Pre-swizzle W1/W2/W3 into MFMA B-fragment order, bf16:
// wf[frag][lane][8], frag = ((conv*3+tap)*4 + kc)*8 + tile
// lane holds B[k = kc*32 + (lane>>4)*8 + e][col = tile*16 + (lane&15)]
// ---------------------------------------------------------------------------
__global__ void prep_wfrag(const float* __restrict__ W1, const float* __restrict__ W2,
                           const float* __restrict__ W3, unsigned short* __restrict__ wf) {
  const int frag = blockIdx.x;           // 0..287
  const int tile = frag & 7;
  const int kc   = (frag >> 3) & 3;
  const int tap  = (frag >> 5) % 3;
  const int conv = frag / 96;
  const float* W = (conv == 0) ? W1 : ((conv == 1) ? W2 : W3);
  const int l   = threadIdx.x;           // 0..63
  const int col = tile * 16 + (l & 15);
  const int k0  = kc * 32 + (l >> 4) * 8;
  bfrag o;
#pragma unroll
  for (int e = 0; e < 8; ++e)
    o[e] = (short)f2bf(W[(size_t)(tap * CCH + k0 + e) * CCH + col]);
  *reinterpret_cast<bfrag*>(wf + (size_t)frag * 512 + l * 8) = o;
}

// ---------------------------------------------------------------------------
// Features fp32 -> bf16 (row N = zeros, the sentinel row)
// ---------------------------------------------------------------------------
__global__ void prep_bf16(const float* __restrict__ feats, unsigned short* __restrict__ fbf) {
  const size_t base = ((size_t)blockIdx.x * 256 + threadIdx.x) * 8;
  const f4 x = *reinterpret_cast<const f4*>(feats + base);
  const f4 y = *reinterpret_cast<const f4*>(feats + base + 4);
  *reinterpret_cast<bfrag*>(fbf + base) = pack8(x, y);
  if (blockIdx.x == 0 && threadIdx.x < 16) {
    bfrag z = {0, 0, 0, 0, 0, 0, 0, 0};
    *reinterpret_cast<bfrag*>(fbf + (size_t)NVOX * CCH + threadIdx.x * 8) = z;
  }
}

// ---------------------------------------------------------------------------
// v2 main kernel: BM=128 rows/block, 512 threads (8 waves, wave = 32r x 64c),
// 2-phase pipelined taps, A gathered via global_load_lds with XOR-swizzled
// per-lane global source, B staged fragment-ordered.
// Branch order: conv-z (W1) -> act chain -> conv-x (W3) -> act -> conv-y (W2)
// accumulated raw directly into the running sum.
// ---------------------------------------------------------------------------
__global__ __launch_bounds__(512, 2)
void recon_v2(const unsigned short* __restrict__ fbf,
              const float* __restrict__ feats,
              const unsigned short* __restrict__ wfrag,
              const int* __restrict__ nbrz, const int* __restrict__ nbry,
              const int* __restrict__ nbrx,
              const float* __restrict__ g0, const float* __restrict__ b0,
              const float* __restrict__ m0, const float* __restrict__ v0,
              const float* __restrict__ g2, const float* __restrict__ b2,
              const float* __restrict__ m2, const float* __restrict__ v2,
              const float* __restrict__ g3, const float* __restrict__ b3,
              const float* __restrict__ m3, const float* __restrict__ v3,
              float* __restrict__ out) {
  __shared__ unsigned short Ab[2][128][128];   // 64 KB, linear rows of 256B
  __shared__ unsigned short Bb[2][16384];      // 64 KB, fragment-ordered

  const int tid  = threadIdx.x;
  const int lane = tid & 63;
  const int w    = tid >> 6;       // wave 0..7
  const int wr   = w >> 1;         // 32-row block 0..3
  const int wc   = w & 1;          // 64-col half 0..1
  const int row0 = blockIdx.x * 128;
  const int l15  = lane & 15;
  const int lhi  = lane >> 4;      // 0..3

  // BN constants for this thread's 4 columns
  float sc0[4], sh0[4], sc2[4], sh2[4], sc3[4], sh3[4];
#pragma unroll
  for (int ct = 0; ct < 4; ++ct) {
    const int col = wc * 64 + ct * 16 + l15;
    sc0[ct] = g0[col] * rsqrtf(v0[col] + BN_EPS); sh0[ct] = b0[col] - m0[col] * sc0[ct];
    sc2[ct] = g2[col] * rsqrtf(v2[col] + BN_EPS); sh2[ct] = b2[col] - m2[col] * sc2[ct];
    sc3[ct] = g3[col] * rsqrtf(v3[col] + BN_EPS); sh3[ct] = b3[col] - m3[col] * sc3[ct];
  }

  f4 acc[2][4], run[2][4];
#pragma unroll
  for (int rt = 0; rt < 2; ++rt)
#pragma unroll
    for (int ct = 0; ct < 4; ++ct) {
      acc[rt][ct] = f4{0.f, 0.f, 0.f, 0.f};
      run[rt][ct] = f4{0.f, 0.f, 0.f, 0.f};
    }

  const int* nbrs[3]  = { nbrz, nbrx, nbry };  // processing order: z, x, y
  const int  wconv[3] = { 0, 2, 1 };           // W-frag region per order slot

  auto stage = [&](int buf, int s) {
    const int cs  = s / 3;
    const int tap = s - cs * 3;
    const int* nb = nbrs[cs];
    const unsigned short* wsrc = wfrag + (((size_t)(wconv[cs] * 3 + tap)) << 14);
    // B: 4 x 1KB fragments per wave (linear, L2-resident)
#pragma unroll
    for (int i = 0; i < 4; ++i) {
      const int frag = w * 4 + i;
      __builtin_amdgcn_global_load_lds(
          (const __attribute__((address_space(1))) void*)(wsrc + frag * 512 + lane * 8),
          (__attribute__((address_space(3))) void*)((char*)&Bb[buf][0] + frag * 1024),
          16, 0, 0);
    }
    // A: 4 issues x 4 rows per wave; per-lane swizzled global source,
    // linear LDS destination. Sentinel idx==NVOX hits the zero row of fbf.
#pragma unroll
    for (int i = 0; i < 4; ++i) {
      const int rloc = w * 16 + i * 4 + lhi;
      const int idx  = nb[(row0 + rloc) * 3 + tap];
      const int cb   = (l15 << 4) ^ ((rloc & 7) << 4);
      __builtin_amdgcn_global_load_lds(
          (const __attribute__((address_space(1))) void*)(fbf + ((size_t)idx << 7) + (cb >> 1)),
          (__attribute__((address_space(3))) void*)((char*)&Ab[buf][w * 16 + i * 4][0]),
          16, 0, 0);
    }
  };

  auto compute = [&](int buf, f4 (*tgt)[4]) {
#pragma unroll
    for (int kc = 0; kc < 4; ++kc) {
      bfrag a0, a1;
      {
        const int r0w = wr * 32 + l15;
        const int c0  = (kc * 64 + (lhi << 4)) ^ ((r0w & 7) << 4);
        a0 = *reinterpret_cast<const bfrag*>((const char*)&Ab[buf][0][0] + r0w * 256 + c0);
        const int r1w = r0w + 16;
        const int c1  = (kc * 64 + (lhi << 4)) ^ ((r1w & 7) << 4);
        a1 = *reinterpret_cast<const bfrag*>((const char*)&Ab[buf][0][0] + r1w * 256 + c1);
      }
#pragma unroll
      for (int ct = 0; ct < 4; ++ct) {
        const bfrag b = *reinterpret_cast<const bfrag*>(
            &Bb[buf][(kc * 8 + wc * 4 + ct) * 512 + lane * 8]);
        tgt[0][ct] = __builtin_amdgcn_mfma_f32_16x16x32_bf16(a0, b, tgt[0][ct], 0, 0, 0);
        tgt[1][ct] = __builtin_amdgcn_mfma_f32_16x16x32_bf16(a1, b, tgt[1][ct], 0, 0, 0);
      }
    }
  };

  stage(0, 0);
  asm volatile("s_waitcnt vmcnt(0)" ::: "memory");
  __syncthreads();

  int buf = 0;
#pragma unroll
  for (int s = 0; s < 9; ++s) {
    if (s < 8) stage(buf ^ 1, s + 1);       // prefetch next tap into other buffer
    compute(buf, (s >= 6) ? run : acc);     // conv-y accumulates raw into run
    if (s == 2) {                           // end of conv-z: double BN+sigmoid chain
#pragma unroll
      for (int rt = 0; rt < 2; ++rt)
#pragma unroll
        for (int ct = 0; ct < 4; ++ct)
#pragma unroll
          for (int j = 0; j < 4; ++j) {
            float u = sigmoidf_(sc0[ct] * acc[rt][ct][j] + sh0[ct]);
            run[rt][ct][j] = sigmoidf_(sc2[ct] * u + sh2[ct]);
            acc[rt][ct][j] = 0.f;
          }
    }
    if (s == 5) {                           // end of conv-x: BN3+sigmoid
#pragma unroll
      for (int rt = 0; rt < 2; ++rt)
#pragma unroll
        for (int ct = 0; ct < 4; ++ct)
#pragma unroll
          for (int j = 0; j < 4; ++j)
            run[rt][ct][j] += sigmoidf_(sc3[ct] * acc[rt][ct][j] + sh3[ct]);
    }
    asm volatile("s_waitcnt vmcnt(0)" ::: "memory");
    __syncthreads();
    buf ^= 1;
  }

  // epilogue: multiply by exact fp32 features, store
#pragma unroll
  for (int rt = 0; rt < 2; ++rt)
#pragma unroll
    for (int ct = 0; ct < 4; ++ct)
#pragma unroll
      for (int j = 0; j < 4; ++j) {
        const int row = row0 + wr * 32 + rt * 16 + (lhi << 2) + j;
        const int col = wc * 64 + ct * 16 + l15;
        const size_t o = ((size_t)row << 7) + col;
        out[o] = run[rt][ct][j] * feats[o];
      }
}

// ---------------------------------------------------------------------------
// v1 main kernel (fallback when ws can't hold bf16 features): passed at 232us
// ---------------------------------------------------------------------------
__global__ __launch_bounds__(256, 2)
void recon_main(const float* __restrict__ feats,
                const int* __restrict__ nbrz, const int* __restrict__ nbry,
                const int* __restrict__ nbrx,
                const unsigned short* __restrict__ wfrag,
                const float* __restrict__ g0, const float* __restrict__ b0,
                const float* __restrict__ m0, const float* __restrict__ v0,
                const float* __restrict__ g2, const float* __restrict__ b2,
                const float* __restrict__ m2, const float* __restrict__ v2,
                const float* __restrict__ g3, const float* __restrict__ b3,
                const float* __restrict__ m3, const float* __restrict__ v3,
                float* __restrict__ out) {
  __shared__ unsigned short Alds[64][136];
  __shared__ unsigned short Blds[16384];

  const int tid  = threadIdx.x;
  const int lane = tid & 63;
  const int wave = tid >> 6;
  const int row0 = blockIdx.x * 64;

  f4 acc[3][8];
#pragma unroll
  for (int c = 0; c < 3; ++c)
#pragma unroll
    for (int t = 0; t < 8; ++t) acc[c][t] = f4{0.f, 0.f, 0.f, 0.f};

  const int gr   = tid >> 2;
  const int gch  = (tid & 3) * 32;
  const int arow = wave * 16 + (lane & 15);
  const int asub = (lane >> 4) * 8;

#pragma unroll
  for (int conv = 0; conv < 3; ++conv) {
    const int* nbr = (conv == 0) ? nbrz : ((conv == 1) ? nbry : nbrx);
    for (int tap = 0; tap < 3; ++tap) {
      {
        const unsigned short* src = wfrag + ((size_t)(conv * 3 + tap) << 14);
#pragma unroll
        for (int i = 0; i < 8; ++i) {
          const int off = (wave << 13) + (i << 10);
          __builtin_amdgcn_global_load_lds(
              (const __attribute__((address_space(1))) void*)(src + (off >> 1) + lane * 8),
              (__attribute__((address_space(3))) void*)((char*)Blds + off),
              16, 0, 0);
        }
      }
      {
        const int idx    = nbr[(row0 + gr) * 3 + tap];
        const bool valid = ((unsigned)idx < (unsigned)NVOX);
        const float* src = feats + ((size_t)(valid ? idx : 0) << 7) + gch;
        const float zm   = valid ? 1.f : 0.f;
#pragma unroll
        for (int j = 0; j < 4; ++j) {
          f4 x = *reinterpret_cast<const f4*>(src + j * 8);
          f4 y = *reinterpret_cast<const f4*>(src + j * 8 + 4);
          x *= zm; y *= zm;
          *reinterpret_cast<bfrag*>(&Alds[gr][gch + j * 8]) = pack8(x, y);
        }
      }
      __syncthreads();
#pragma unroll
      for (int kc = 0; kc < 4; ++kc) {
        const bfrag a = *reinterpret_cast<const bfrag*>(&Alds[arow][kc * 32 + asub]);
#pragma unroll
        for (int t = 0; t < 8; ++t) {
          const bfrag b = *reinterpret_cast<const bfrag*>(
              &Blds[(((kc << 3) + t) << 9) + lane * 8]);
          acc[conv][t] = __builtin_amdgcn_mfma_f32_16x16x32_bf16(a, b, acc[conv][t], 0, 0, 0);
        }
      }
      __syncthreads();
    }
  }

  const int colb = lane & 15;
  const int rb   = row0 + wave * 16 + ((lane >> 4) << 2);
#pragma unroll
  for (int t = 0; t < 8; ++t) {
    const int col = t * 16 + colb;
    const float sc0 = g0[col] * rsqrtf(v0[col] + BN_EPS);
    const float sh0 = b0[col] - m0[col] * sc0;
    const float sc2 = g2[col] * rsqrtf(v2[col] + BN_EPS);
    const float sh2 = b2[col] - m2[col] * sc2;
    const float sc3 = g3[col] * rsqrtf(v3[col] + BN_EPS);
    const float sh3 = b3[col] - m3[col] * sc3;
#pragma unroll
    for (int j = 0; j < 4; ++j) {
      const int row = rb + j;
      float u = sigmoidf_(sc0 * acc[0][t][j] + sh0);
      u       = sigmoidf_(sc2 * u + sh2);
      const float s3v  = sigmoidf_(sc3 * acc[2][t][j] + sh3);
      const float ssum = u + acc[1][t][j] + s3v;
      const size_t o   = ((size_t)row << 7) + col;
      out[o] = ssum * feats[o];
    }
  }
}

// ---------------------------------------------------------------------------
// Last-resort fallback: exact fp32
// ---------------------------------------------------------------------------
__global__ void recon_naive(const float* __restrict__ feats,
    const float* __restrict__ W1, const float* __restrict__ W2, const float* __restrict__ W3,
    const int* __restrict__ nbrz, const int* __restrict__ nbry, const int* __restrict__ nbrx,
    const float* g0, const float* b0, const float* m0, const float* v0,
    const float* g2, const float* b2, const float* m2, const float* v2,
    const float* g3, const float* b3, const float* m3, const float* v3,
    float* __restrict__ out) {
  __shared__ float rows[3][CCH];
  const int n = blockIdx.x;
  const int d = threadIdx.x;
  float res[3];
#pragma unroll
  for (int conv = 0; conv < 3; ++conv) {
    const int* nbr  = (conv == 0) ? nbrz : ((conv == 1) ? nbry : nbrx);
    const float* W  = (conv == 0) ? W1 : ((conv == 1) ? W2 : W3);
#pragma unroll
    for (int tap = 0; tap < 3; ++tap) {
      const int idx = nbr[n * 3 + tap];
      rows[tap][d] = ((unsigned)idx < (unsigned)NVOX) ? feats[((size_t)idx << 7) + d] : 0.f;
    }
    __syncthreads();
    const float* rflat = &rows[0][0];
    float s = 0.f;
    for (int k = 0; k < 3 * CCH; ++k) s += rflat[k] * W[(size_t)k * CCH + d];
    res[conv] = s;
    __syncthreads();
  }
  const float sc0 = g0[d] * rsqrtf(v0[d] + BN_EPS), sh0 = b0[d] - m0[d] * sc0;
  const float sc2 = g2[d] * rsqrtf(v2[d] + BN_EPS), sh2 = b2[d] - m2[d] * sc2;
  const float sc3 = g3[d] * rsqrtf(v3[d] + BN_EPS), sh3 = b3[d] - m3[d] * sc3;
  float u = sigmoidf_(sc0 * res[0] + sh0);
  u = sigmoidf_(sc2 * u + sh2);
  const float s3v = sigmoidf_(sc3 * res[2] + sh3);
  out[((size_t)n << 7) + d] = (u + res[1] + s3v) * feats[((size_t)n << 7) + d];
}

extern "C" void kernel_launch(void* const* d_in, const int* in_sizes, int n_in,
                              void* d_out, int out_size, void* d_ws, size_t ws_size,
                              hipStream_t stream) {
  const float* feats = (const float*)d_in[0];
  const float* W1 = (const float*)d_in[1];
  const float* W2 = (const float*)d_in[2];
  const float* W3 = (const float*)d_in[3];
  const float* g0 = (const float*)d_in[4];
  const float* b0 = (const float*)d_in[5];
  const float* m0 = (const float*)d_in[6];
  const float* v0 = (const float*)d_in[7];
  const float* g2 = (const float*)d_in[8];
  const float* b2 = (const float*)d_in[9];
  const float* m2 = (const float*)d_in[10];
  const float* v2 = (const float*)d_in[11];
  const float* g3 = (const float*)d_in[12];
  const float* b3 = (const float*)d_in[13];
  const float* m3 = (const float*)d_in[14];
  const float* v3 = (const float*)d_in[15];
  const int* nz = (const int*)d_in[16];
  const int* ny = (const int*)d_in[17];
  const int* nx = (const int*)d_in[18];
  float* out = (float*)d_out;

  const size_t wf_bytes = 288u * 1024u;                              // 294912
  const size_t fb_bytes = ((size_t)NVOX + 1) * CCH * sizeof(short);  // 67.1 MB
  if (ws_size >= wf_bytes + fb_bytes) {
    unsigned short* wf  = (unsigned short*)d_ws;
    unsigned short* fbf = (unsigned short*)((char*)d_ws + wf_bytes);
    hipLaunchKernelGGL(prep_wfrag, dim3(288), dim3(64), 0, stream, W1, W2, W3, wf);
    hipLaunchKernelGGL(prep_bf16, dim3((NVOX * CCH) / (256 * 8)), dim3(256), 0, stream,
                       feats, fbf);
    hipLaunchKernelGGL(recon_v2, dim3(NVOX / 128), dim3(512), 0, stream,
                       fbf, feats, wf, nz, ny, nx,
                       g0, b0, m0, v0, g2, b2, m2, v2, g3, b3, m3, v3, out);
  } else if (ws_size >= wf_bytes) {
    unsigned short* wf = (unsigned short*)d_ws;
    hipLaunchKernelGGL(prep_wfrag, dim3(288), dim3(64), 0, stream, W1, W2, W3, wf);
    hipLaunchKernelGGL(recon_main, dim3(NVOX / 64), dim3(256), 0, stream,
                       feats, nz, ny, nx, wf,
                       g0, b0, m0, v0, g2, b2, m2, v2, g3, b3, m3, v3, out);
  } else {
    hipLaunchKernelGGL(recon_naive, dim3(NVOX), dim3(CCH), 0, stream,
                       feats, W1, W2, W3, nz, ny, nx,
                       g0, b0, m0, v0, g2, b2, m2, v2, g3, b3, m3, v3, out);
  }
}

// Round 3
// 200.788 us; speedup vs baseline: 1.1579x; 1.0641x over previous
//
#include <hip/hip_runtime.h>
#include <hip/hip_bf16.h>
#include <stdint.h>
#include <stddef.h>

#define NVOX 262144
#define CCH 128
#define BN_EPS 1e-3f

typedef __attribute__((ext_vector_type(8))) short bfrag;   // 8 bf16 = 4 VGPRs
typedef __attribute__((ext_vector_type(4))) float f4;      // 4 f32

#define AS1 __attribute__((address_space(1)))
#define AS3 __attribute__((address_space(3)))

__device__ __forceinline__ unsigned short f2bf(float f) {
  union { float f; unsigned u; } v; v.f = f;
  unsigned r = v.u + 0x7fffu + ((v.u >> 16) & 1u);   // RNE (inputs finite)
  return (unsigned short)(r >> 16);
}

__device__ __forceinline__ bfrag pack8(f4 x, f4 y) {
  bfrag r;
  r[0] = (short)f2bf(x[0]); r[1] = (short)f2bf(x[1]);
  r[2] = (short)f2bf(x[2]); r[3] = (short)f2bf(x[3]);
  r[4] = (short)f2bf(y[0]); r[5] = (short)f2bf(y[1]);
  r[6] = (short)f2bf(y[2]); r[7] = (short)f2bf(y[3]);
  return r;
}

__device__ __forceinline__ float sigmoidf_(float x) {
  return 1.f / (1.f + __expf(-x));
}

__device__ __forceinline__ float bf2f(unsigned short h) {
  union { unsigned u; float f; } v; v.u = ((unsigned)h) << 16; return v.f;
}

// ---------------------------------------------------------------------------
// Pre-swizzle W1/W2/W3 into MFMA B-fragment order, bf16:
// region r = conv*3+tap (conv: 0=W1, 1=W2, 2=W3); frag = (r*4 + kc)*8 + tile
// lane holds B[k = kc*32 + (lane>>4)*8 + e][col = tile*16 + (lane&15)]
// ---------------------------------------------------------------------------
__global__ void prep_wfrag(const float* __restrict__ W1, const float* __restrict__ W2,
                           const float* __restrict__ W3, unsigned short* __restrict__ wf) {
  const int frag = blockIdx.x;           // 0..287
  const int tile = frag & 7;
  const int kc   = (frag >> 3) & 3;
  const int tap  = (frag >> 5) % 3;
  const int conv = frag / 96;
  const float* W = (conv == 0) ? W1 : ((conv == 1) ? W2 : W3);
  const int l   = threadIdx.x;           // 0..63
  const int col = tile * 16 + (l & 15);
  const int k0  = kc * 32 + (l >> 4) * 8;
  bfrag o;
#pragma unroll
  for (int e = 0; e < 8; ++e)
    o[e] = (short)f2bf(W[(size_t)(tap * CCH + k0 + e) * CCH + col]);
  *reinterpret_cast<bfrag*>(wf + (size_t)frag * 512 + l * 8) = o;
}

// ---------------------------------------------------------------------------
// BN scale/shift tables: bn[6][128] = {sc0, sh0, sc2, sh2, sc3, sh3}
// ---------------------------------------------------------------------------
__global__ void prep_bn(const float* g0, const float* b0, const float* m0, const float* v0,
                        const float* g2, const float* b2, const float* m2, const float* v2,
                        const float* g3, const float* b3, const float* m3, const float* v3,
                        float* __restrict__ bn) {
  const int c = threadIdx.x;
  const float s0 = g0[c] * rsqrtf(v0[c] + BN_EPS);
  const float s2 = g2[c] * rsqrtf(v2[c] + BN_EPS);
  const float s3 = g3[c] * rsqrtf(v3[c] + BN_EPS);
  bn[0 * CCH + c] = s0; bn[1 * CCH + c] = b0[c] - m0[c] * s0;
  bn[2 * CCH + c] = s2; bn[3 * CCH + c] = b2[c] - m2[c] * s2;
  bn[4 * CCH + c] = s3; bn[5 * CCH + c] = b3[c] - m3[c] * s3;
}

// ---------------------------------------------------------------------------
// Features fp32 -> bf16 (row N = zeros, the sentinel row)
// ---------------------------------------------------------------------------
__global__ void prep_bf16(const float* __restrict__ feats, unsigned short* __restrict__ fbf) {
  const size_t base = ((size_t)blockIdx.x * 256 + threadIdx.x) * 8;
  const f4 x = *reinterpret_cast<const f4*>(feats + base);
  const f4 y = *reinterpret_cast<const f4*>(feats + base + 4);
  *reinterpret_cast<bfrag*>(fbf + base) = pack8(x, y);
  if (blockIdx.x == 0 && threadIdx.x < 16) {
    bfrag z = {0, 0, 0, 0, 0, 0, 0, 0};
    *reinterpret_cast<bfrag*>(fbf + (size_t)NVOX * CCH + threadIdx.x * 8) = z;
  }
}

// ---------------------------------------------------------------------------
// v3: BM=128, 512 threads (8 waves: wave = 32r x 64c). A triple-buffered,
// B double-buffered (160 KB LDS). All nbr indices preloaded to registers.
// Counted vmcnt (never 0 mid-loop), raw barriers, 3 separate acc sets,
// all activations in the epilogue (no param loads inside the loop).
// Slot order s=0..8: conv-z(W1) taps 0-2, conv-x(W3) taps 0-2, conv-y(W2) taps 0-2.
// ---------------------------------------------------------------------------
__global__ __launch_bounds__(512, 2)
void recon_v3(const unsigned short* __restrict__ fbf,
              const unsigned short* __restrict__ wfrag,
              const float* __restrict__ bn,
              const int* __restrict__ nbrz, const int* __restrict__ nbrx,
              const int* __restrict__ nbry,
              float* __restrict__ out) {
  __shared__ unsigned short Aa[3][128][128];   // 96 KB
  __shared__ unsigned short Bb[2][16384];      // 64 KB

  const int tid  = threadIdx.x;
  const int lane = tid & 63;
  const int w    = tid >> 6;       // wave 0..7
  const int wr   = w >> 1;         // 32-row block 0..3
  const int wc   = w & 1;          // 64-col half 0..1
  const int row0 = blockIdx.x * 128;
  const int l15  = lane & 15;
  const int lhi  = lane >> 4;      // 0..3

  // W-fragment region per slot: slots 0-2 -> W1 (regions 0-2),
  // slots 3-5 -> W3 (regions 6-8), slots 6-8 -> W2 (regions 3-5).
  constexpr int wfc[9] = {0, 1, 2, 6, 7, 8, 3, 4, 5};

  // ---- prologue: preload all 36 neighbor indices ----
  int idxs[9][4];
#pragma unroll
  for (int i = 0; i < 4; ++i) {
    const int rg = (row0 + w * 16 + i * 4 + lhi) * 3;
    idxs[0][i] = nbrz[rg + 0]; idxs[1][i] = nbrz[rg + 1]; idxs[2][i] = nbrz[rg + 2];
    idxs[3][i] = nbrx[rg + 0]; idxs[4][i] = nbrx[rg + 1]; idxs[5][i] = nbrx[rg + 2];
    idxs[6][i] = nbry[rg + 0]; idxs[7][i] = nbry[rg + 1]; idxs[8][i] = nbry[rg + 2];
  }
  asm volatile("s_waitcnt vmcnt(0)" ::: "memory");
  __builtin_amdgcn_sched_barrier(0);

  f4 acc0[2][4], acc1[2][4], acc2[2][4];
#pragma unroll
  for (int rt = 0; rt < 2; ++rt)
#pragma unroll
    for (int ct = 0; ct < 4; ++ct) {
      acc0[rt][ct] = f4{0.f, 0.f, 0.f, 0.f};
      acc1[rt][ct] = f4{0.f, 0.f, 0.f, 0.f};
      acc2[rt][ct] = f4{0.f, 0.f, 0.f, 0.f};
    }

  auto stageB = [&](int buf, int slot) {
    const unsigned short* wsrc = wfrag + ((size_t)wfc[slot] << 14);
#pragma unroll
    for (int i = 0; i < 4; ++i) {
      const int frag = w * 4 + i;
      __builtin_amdgcn_global_load_lds(
          (const AS1 void*)(wsrc + frag * 512 + lane * 8),
          (AS3 void*)((char*)&Bb[0][0] + buf * 32768 + frag * 1024), 16, 0, 0);
    }
  };

  auto stageA = [&](int buf, int slot) {
#pragma unroll
    for (int i = 0; i < 4; ++i) {
      const int rloc = w * 16 + i * 4 + lhi;
      const int cb   = (l15 << 4) ^ ((rloc & 7) << 4);   // pre-swizzled source bytes
      __builtin_amdgcn_global_load_lds(
          (const AS1 void*)(fbf + ((size_t)idxs[slot][i] << 7) + (cb >> 1)),
          (AS3 void*)((char*)&Aa[0][0][0] + buf * 32768 + (w * 16 + i * 4) * 256),
          16, 0, 0);
    }
  };

  auto computeS = [&](int abuf, int bbuf, f4 (*tgt)[4]) {
#pragma unroll
    for (int kc = 0; kc < 4; ++kc) {
      const int r0w = wr * 32 + l15;
      const int c0  = (kc * 64 + (lhi << 4)) ^ ((r0w & 7) << 4);
      const bfrag a0 = *reinterpret_cast<const bfrag*>(
          (const char*)&Aa[0][0][0] + abuf * 32768 + r0w * 256 + c0);
      const int r1w = r0w + 16;
      const int c1  = (kc * 64 + (lhi << 4)) ^ ((r1w & 7) << 4);
      const bfrag a1 = *reinterpret_cast<const bfrag*>(
          (const char*)&Aa[0][0][0] + abuf * 32768 + r1w * 256 + c1);
#pragma unroll
      for (int ct = 0; ct < 4; ++ct) {
        const bfrag b = *reinterpret_cast<const bfrag*>(
            (const char*)&Bb[0][0] + bbuf * 32768 + (kc * 8 + wc * 4 + ct) * 1024 + lane * 16);
        tgt[0][ct] = __builtin_amdgcn_mfma_f32_16x16x32_bf16(a0, b, tgt[0][ct], 0, 0, 0);
        tgt[1][ct] = __builtin_amdgcn_mfma_f32_16x16x32_bf16(a1, b, tgt[1][ct], 0, 0, 0);
      }
    }
  };

  // ---- prologue staging: B(0), A(0), A(1) -> 12 outstanding ----
  stageB(0, 0);
  stageA(0, 0);
  stageA(1, 1);

  // Phase S: issue B(S+1), A(S+2); wait counted; barrier; MFMA; barrier.
#define PHASE(S, ACCSET, VMC)                                          \
  {                                                                    \
    if ((S) < 8) stageB(((S) + 1) & 1, (S) + 1);                       \
    if ((S) < 7) stageA(((S) + 2) % 3, (S) + 2);                       \
    asm volatile("s_waitcnt vmcnt(" VMC ")" ::: "memory");             \
    __builtin_amdgcn_sched_barrier(0);                                 \
    __builtin_amdgcn_s_barrier();                                      \
    __builtin_amdgcn_sched_barrier(0);                                 \
    __builtin_amdgcn_s_setprio(1);                                     \
    computeS((S) % 3, (S) & 1, ACCSET);                                \
    __builtin_amdgcn_s_setprio(0);                                     \
    asm volatile("s_waitcnt lgkmcnt(0)" ::: "memory");                 \
    __builtin_amdgcn_sched_barrier(0);                                 \
    __builtin_amdgcn_s_barrier();                                      \
    __builtin_amdgcn_sched_barrier(0);                                 \
  }

  PHASE(0, acc0, "12")
  PHASE(1, acc0, "12")
  PHASE(2, acc0, "12")
  PHASE(3, acc1, "12")
  PHASE(4, acc1, "12")
  PHASE(5, acc1, "12")
  PHASE(6, acc2, "12")
  PHASE(7, acc2, "8")
  PHASE(8, acc2, "0")
#undef PHASE

  // ---- epilogue: BN+sigmoid chains from the precomputed table; multiply by
  // bf16 features (L3-hot); store fp32 out ----
#pragma unroll
  for (int ct = 0; ct < 4; ++ct) {
    const int col = wc * 64 + ct * 16 + l15;
    const float sc0 = bn[0 * CCH + col], sh0 = bn[1 * CCH + col];
    const float sc2 = bn[2 * CCH + col], sh2 = bn[3 * CCH + col];
    const float sc3 = bn[4 * CCH + col], sh3 = bn[5 * CCH + col];
#pragma unroll
    for (int rt = 0; rt < 2; ++rt)
#pragma unroll
      for (int j = 0; j < 4; ++j) {
        const int row = row0 + wr * 32 + rt * 16 + (lhi << 2) + j;
        float u = sigmoidf_(sc0 * ((ct < 4) ? (rt == 0 ? acc0[0][ct][j] : acc0[1][ct][j])
                                            : 0.f) + sh0);
        u = sigmoidf_(sc2 * u + sh2);
        const float s3v = sigmoidf_(sc3 * (rt == 0 ? acc1[0][ct][j] : acc1[1][ct][j]) + sh3);
        const float s2v = (rt == 0 ? acc2[0][ct][j] : acc2[1][ct][j]);
        const size_t o  = ((size_t)row << 7) + col;
        out[o] = (u + s2v + s3v) * bf2f(fbf[o]);
      }
  }
}

// ---------------------------------------------------------------------------
// Last-resort fallback: exact fp32
// ---------------------------------------------------------------------------
__global__ void recon_naive(const float* __restrict__ feats,
    const float* __restrict__ W1, const float* __restrict__ W2, const float* __restrict__ W3,
    const int* __restrict__ nbrz, const int* __restrict__ nbry, const int* __restrict__ nbrx,
    const float* g0, const float* b0, const float* m0, const float* v0,
    const float* g2, const float* b2, const float* m2, const float* v2,
    const float* g3, const float* b3, const float* m3, const float* v3,
    float* __restrict__ out) {
  __shared__ float rows[3][CCH];
  const int n = blockIdx.x;
  const int d = threadIdx.x;
  float res[3];
#pragma unroll
  for (int conv = 0; conv < 3; ++conv) {
    const int* nbr  = (conv == 0) ? nbrz : ((conv == 1) ? nbry : nbrx);
    const float* W  = (conv == 0) ? W1 : ((conv == 1) ? W2 : W3);
#pragma unroll
    for (int tap = 0; tap < 3; ++tap) {
      const int idx = nbr[n * 3 + tap];
      rows[tap][d] = ((unsigned)idx < (unsigned)NVOX) ? feats[((size_t)idx << 7) + d] : 0.f;
    }
    __syncthreads();
    const float* rflat = &rows[0][0];
    float s = 0.f;
    for (int k = 0; k < 3 * CCH; ++k) s += rflat[k] * W[(size_t)k * CCH + d];
    res[conv] = s;
    __syncthreads();
  }
  const float sc0 = g0[d] * rsqrtf(v0[d] + BN_EPS), sh0 = b0[d] - m0[d] * sc0;
  const float sc2 = g2[d] * rsqrtf(v2[d] + BN_EPS), sh2 = b2[d] - m2[d] * sc2;
  const float sc3 = g3[d] * rsqrtf(v3[d] + BN_EPS), sh3 = b3[d] - m3[d] * sc3;
  float u = sigmoidf_(sc0 * res[0] + sh0);
  u = sigmoidf_(sc2 * u + sh2);
  const float s3v = sigmoidf_(sc3 * res[2] + sh3);
  out[((size_t)n << 7) + d] = (u + res[1] + s3v) * feats[((size_t)n << 7) + d];
}

extern "C" void kernel_launch(void* const* d_in, const int* in_sizes, int n_in,
                              void* d_out, int out_size, void* d_ws, size_t ws_size,
                              hipStream_t stream) {
  const float* feats = (const float*)d_in[0];
  const float* W1 = (const float*)d_in[1];
  const float* W2 = (const float*)d_in[2];
  const float* W3 = (const float*)d_in[3];
  const float* g0 = (const float*)d_in[4];
  const float* b0 = (const float*)d_in[5];
  const float* m0 = (const float*)d_in[6];
  const float* v0 = (const float*)d_in[7];
  const float* g2 = (const float*)d_in[8];
  const float* b2 = (const float*)d_in[9];
  const float* m2 = (const float*)d_in[10];
  const float* v2 = (const float*)d_in[11];
  const float* g3 = (const float*)d_in[12];
  const float* b3 = (const float*)d_in[13];
  const float* m3 = (const float*)d_in[14];
  const float* v3 = (const float*)d_in[15];
  const int* nz = (const int*)d_in[16];
  const int* ny = (const int*)d_in[17];
  const int* nx = (const int*)d_in[18];
  float* out = (float*)d_out;

  const size_t wf_bytes = 288u * 1024u;                              // 294912
  const size_t bn_bytes = 4096u;                                     // 6*128*4 padded
  const size_t fb_bytes = ((size_t)NVOX + 1) * CCH * sizeof(short);  // 67.1 MB
  if (ws_size >= wf_bytes + bn_bytes + fb_bytes) {
    unsigned short* wf  = (unsigned short*)d_ws;
    float*          bnt = (float*)((char*)d_ws + wf_bytes);
    unsigned short* fbf = (unsigned short*)((char*)d_ws + wf_bytes + bn_bytes);
    hipLaunchKernelGGL(prep_wfrag, dim3(288), dim3(64), 0, stream, W1, W2, W3, wf);
    hipLaunchKernelGGL(prep_bn, dim3(1), dim3(CCH), 0, stream,
                       g0, b0, m0, v0, g2, b2, m2, v2, g3, b3, m3, v3, bnt);
    hipLaunchKernelGGL(prep_bf16, dim3((NVOX * CCH) / (256 * 8)), dim3(256), 0, stream,
                       feats, fbf);
    hipLaunchKernelGGL(recon_v3, dim3(NVOX / 128), dim3(512), 0, stream,
                       fbf, wf, bnt, nz, nx, ny, out);
  } else {
    hipLaunchKernelGGL(recon_naive, dim3(NVOX), dim3(CCH), 0, stream,
                       feats, W1, W2, W3, nz, ny, nx,
                       g0, b0, m0, v0, g2, b2, m2, v2, g3, b3, m3, v3, out);
  }
}